// Round 11
// baseline (105.231 us; speedup 1.0000x reference)
//
#include <hip/hip_runtime.h>
#include <math.h>

// DAS beamforming: out[b][c][p] = sum_s data[b][c][s][t(s,p)]
// Table chain: ONLY the f64-emulated chain is proven bit-exact (r5/r6/r8/r10).
// r7's native-f32 version regressed. DO NOT change delay_entry.
// r10 evidence: harness re-poison fill of 256MiB ws = 43us inside timed region
// (uncontrollable). Gather cost model (fits r5/r6/r8/r9/r10):
//   per-CU cycles = sum over VMEM wave-instrs of (10 + 1.4*lines_touched),
//   TD-serialized; VALU/occupancy are spectators.
// r11: 2 px/thread (iy pair) -> tab = ONE dwordx2 per thread per sensor
// (adjacent iy need adjacent u16 entries; multi-dword loads need only 4B
// alignment) -> tab wave-instrs halved. Gathers unchanged (bf16 8ch x 16B).
// prep vectorized 4-wide. Output pairs stored as float2.

#define NXY 512
#define S_CNT 128
#define T_CNT 2048
#define CH 8                       // B*2 = 4*2
#define CH_STRIDE (S_CNT * T_CNT)  // 262144 floats between channels (orig layout)
#define NPIX (NXY * NXY)
#define TAB_BYTES (NPIX * 2)       // 512 KB u16 table

#pragma float_control(push)
#pragma float_control(precise, on)
__device__ __forceinline__ unsigned short delay_entry(int adx, int ady) {
    const double DX32 = (double)1e-4f;                        // f32 const, exact widen
    const double R1 = (double)(float)(1.0 / 1550.0);          // CR f32 reciprocal
    const double R2 = (double)(float)(1.0 / (double)2.5e-8f); // = 4.0e7 exactly
    float dxf = (float)((double)adx * DX32);        // exact f64 product -> f32 round
    float dyf = (float)((double)ady * DX32);
    float a2 = (float)((double)dxf * (double)dxf);  // exact in f64 -> f32 round
    float b2 = (float)((double)dyf * (double)dyf);
    float sum = (float)((double)a2 + (double)b2);   // exact in f64 -> f32 round
    float dis = (float)sqrt((double)sum);           // CR f32 sqrt via Figueroa
    float q1 = (float)((double)dis * R1);           // CR f32 mul (exact f64 product)
    float q2 = (float)((double)q1 * R2);            // CR f32 mul (exact f64 product)
    return (unsigned short)(int)q2;                 // trunc = convert<s32>; max 1864
}

__device__ __forceinline__ unsigned int bf16_rne(float f) {
    unsigned int x = __float_as_uint(f);
    return (x + 0x7fffu + ((x >> 16) & 1u)) >> 16;  // round-to-nearest-even
}

// Fused prep, 4 slots/thread: table entries (ushort4 store) + transpose-convert
// (8ch,128s,2048t)f32 -> (128s,2048t) x (8ch bf16 in 16B).
__global__ __launch_bounds__(256) void prep(const float* __restrict__ data,
                                            unsigned short* __restrict__ tab,
                                            uint4* __restrict__ d2b) {
    int i0 = (blockIdx.x * 256 + threadIdx.x) * 4;  // 0..262140, 4-aligned
    // --- 4 table entries (same adx row: 512 | 4) ---
    int adx = i0 >> 9;
    int ady0 = i0 & 511;
    ushort4 te;
    te.x = delay_entry(adx, ady0);
    te.y = delay_entry(adx, ady0 + 1);
    te.z = delay_entry(adx, ady0 + 2);
    te.w = delay_entry(adx, ady0 + 3);
    *(ushort4*)(tab + i0) = te;

    // --- transpose-convert 4 consecutive t-slots ---
    float4 v[CH];
#pragma unroll
    for (int k = 0; k < CH; ++k) v[k] = *(const float4*)(data + k * CH_STRIDE + i0);
#pragma unroll
    for (int j = 0; j < 4; ++j) {
        const float* c = (const float*)v;  // v[k] components: c[4k+j]
        unsigned int w0 = bf16_rne(c[0 * 4 + j]) | (bf16_rne(c[1 * 4 + j]) << 16);
        unsigned int w1 = bf16_rne(c[2 * 4 + j]) | (bf16_rne(c[3 * 4 + j]) << 16);
        unsigned int w2 = bf16_rne(c[4 * 4 + j]) | (bf16_rne(c[5 * 4 + j]) << 16);
        unsigned int w3 = bf16_rne(c[6 * 4 + j]) | (bf16_rne(c[7 * 4 + j]) << 16);
        d2b[i0 + j] = make_uint4(w0, w1, w2, w3);
    }
}
#pragma float_control(pop)

__device__ __forceinline__ float bflo(unsigned int u) { return __uint_as_float(u << 16); }
__device__ __forceinline__ float bfhi(unsigned int u) { return __uint_as_float(u & 0xffff0000u); }

// Gather: 1 thread = 2 iy-adjacent pixels x 8 channels.
// Wave = 8(ix) x 8(iy-pairs) = 8x16 px tile. Block 256 thr = 16ix x 32iy px.
// Tab: one dwordx2 (aligned-down) covers both consecutive entries {m, m+1}.
__global__ __launch_bounds__(256) void das_gather2(const uint4* __restrict__ d2b,
                                                   const unsigned short* __restrict__ tab,
                                                   const int* __restrict__ sxy,
                                                   float* __restrict__ out) {
    __shared__ int sx[S_CNT];
    __shared__ int sy[S_CNT];
    int tid = threadIdx.x;
    if (tid < S_CNT) {
        sx[tid] = sxy[2 * tid];
        sy[tid] = sxy[2 * tid + 1];
    }
    __syncthreads();

    // grid: 32 bx (16-ix tiles) x 16 by (32-iy tiles) = 512 blocks
    int bx = blockIdx.x & 31;
    int by = blockIdx.x >> 5;
    int ix = (bx << 4) | ((tid >> 7) << 3) | ((tid >> 3) & 7);
    int iy0 = (by << 5) | (((tid >> 6) & 1) << 4) | ((tid & 7) << 1);  // even

    float acc0[CH], acc1[CH];
#pragma unroll
    for (int k = 0; k < CH; ++k) { acc0[k] = 0.0f; acc1[k] = 0.0f; }

    const char* tabb = (const char*)tab;

#pragma unroll 4
    for (int s = 0; s < S_CNT; ++s) {
        int dxi = sx[s] - ix;
        int adx = dxi < 0 ? -dxi : dxi;
        int dy0 = sy[s] - iy0;
        int ady0 = dy0 < 0 ? -dy0 : dy0;
        int dy1 = dy0 - 1;
        int ady1 = dy1 < 0 ? -dy1 : dy1;
        int m = ady0 < ady1 ? ady0 : ady1;          // {m, m+1} = {ady0, ady1}
        int boff = (((adx << 9) + m) << 1) & ~3;    // aligned-down dword offset
        uint2 d = *(const uint2*)(tabb + boff);
        unsigned sel = (unsigned)(m & 1);
        unsigned em = sel ? (d.x >> 16) : (d.x & 0xffffu);   // entry[m]
        unsigned em1 = sel ? (d.y & 0xffffu) : (d.x >> 16);  // entry[m+1]
        unsigned t0 = (ady0 == m) ? em : em1;       // t for pixel iy0
        unsigned t1 = (ady0 == m) ? em1 : em;       // t for pixel iy0+1
        uint4 w0 = d2b[(s << 11) + t0];
        uint4 w1 = d2b[(s << 11) + t1];
        acc0[0] += bflo(w0.x);  // per-channel s-ascending: deterministic
        acc0[1] += bfhi(w0.x);
        acc0[2] += bflo(w0.y);
        acc0[3] += bfhi(w0.y);
        acc0[4] += bflo(w0.z);
        acc0[5] += bfhi(w0.z);
        acc0[6] += bflo(w0.w);
        acc0[7] += bfhi(w0.w);
        acc1[0] += bflo(w1.x);
        acc1[1] += bfhi(w1.x);
        acc1[2] += bflo(w1.y);
        acc1[3] += bfhi(w1.y);
        acc1[4] += bflo(w1.z);
        acc1[5] += bfhi(w1.z);
        acc1[6] += bflo(w1.w);
        acc1[7] += bfhi(w1.w);
    }

    int pix = (ix << 9) | iy0;  // iy0, iy0+1 adjacent -> float2 store per channel
#pragma unroll
    for (int k = 0; k < CH; ++k) {
        *(float2*)(out + k * NPIX + pix) = make_float2(acc0[k], acc1[k]);
    }
}

// ---------- fallback path (ws too small): r5-proven build_table + das_main ----------
#pragma float_control(push)
#pragma float_control(precise, on)
__global__ __launch_bounds__(256) void build_table(unsigned short* __restrict__ tab) {
    int idx = blockIdx.x * 256 + threadIdx.x;
    tab[idx] = delay_entry(idx >> 9, idx & 511);
}
#pragma float_control(pop)

__global__ __launch_bounds__(256) void das_main(const float* __restrict__ data,
                                                const unsigned short* __restrict__ tab,
                                                const int* __restrict__ sxy,
                                                float* __restrict__ out) {
    __shared__ int sx[S_CNT];
    __shared__ int sy[S_CNT];
    int tid = threadIdx.x;
    if (tid < S_CNT) {
        sx[tid] = sxy[2 * tid];
        sy[tid] = sxy[2 * tid + 1];
    }
    __syncthreads();
    int iy = ((blockIdx.x & 31) << 4) | (tid & 15);
    int ix = ((blockIdx.x >> 5) << 4) | (tid >> 4);
    float acc[CH];
#pragma unroll
    for (int k = 0; k < CH; ++k) acc[k] = 0.0f;
#pragma unroll 4
    for (int s = 0; s < S_CNT; ++s) {
        int dxi = sx[s] - ix;
        int dyi = sy[s] - iy;
        int adx = dxi < 0 ? -dxi : dxi;
        int ady = dyi < 0 ? -dyi : dyi;
        int t = (int)tab[(adx << 9) | ady];
        const float* p = data + (s << 11) + t;
#pragma unroll
        for (int k = 0; k < CH; ++k) acc[k] += p[(size_t)k * CH_STRIDE];
    }
    int pix = (ix << 9) | iy;
#pragma unroll
    for (int k = 0; k < CH; ++k) out[k * NPIX + pix] = acc[k];
}

extern "C" void kernel_launch(void* const* d_in, const int* in_sizes, int n_in,
                              void* d_out, int out_size, void* d_ws, size_t ws_size,
                              hipStream_t stream) {
    const float* data = (const float*)d_in[0];     // (4,2,128,2048) f32
    const int* sxy = (const int*)d_in[1];          // (128,2) i32
    float* out = (float*)d_out;                    // (4,2,512,512) f32
    unsigned short* tab = (unsigned short*)d_ws;   // 512 KB

    size_t need = (size_t)TAB_BYTES + (size_t)CH_STRIDE * 16;  // 512KB + 4MB
    if (ws_size >= need) {
        uint4* d2b = (uint4*)((char*)d_ws + TAB_BYTES);
        prep<<<NPIX / 1024, 256, 0, stream>>>(data, tab, d2b);
        das_gather2<<<512, 256, 0, stream>>>(d2b, tab, sxy, out);
    } else {
        build_table<<<NPIX / 256, 256, 0, stream>>>(tab);
        das_main<<<1024, 256, 0, stream>>>(data, tab, sxy, out);
    }
}